// Round 9
// baseline (913.288 us; speedup 1.0000x reference)
//
#include <hip/hip_runtime.h>

#define HD 64
#define SLOPE 0.01f
#define BSH 6                    // 64 nodes per bucket
#define BNODES 64
#define CHUNK 4096               // edges per partition chunk
#define SLOT 1536                // padded edge capacity per bucket (exp max ~1150)
#define SIDX 1280                // LDS-staged colidx capacity (5KB)

// ---------------------------------------------------------------------------
// R9: ONE fused kernel: part -> bsort(+x->fp16) -> L1 -> L2 -> L3-out.
// Software grid barrier (regular launch; R5 showed hipLaunchCooperativeKernel
// silently no-ops under graph capture -> out stayed zeroed, absmax=max|ref|).
// Co-residency: LDS = 39936B exactly -> 4 blocks/CU -> capacity 1024 >= 782.
// Barrier does device fence (wbl2/inv) around atomicAdd+spin — replicates
// the implicit cache ops at kernel boundaries (per-XCD L2 non-coherence).
// Layer bodies = R7-verified (R8's merged loop spilled: VGPR 64 + 50MB
// scratch traffic -> reverted). sS carries f32 h across layers; sidx staged
// once; 3 h16 buffers (a->b->c) avoid read-after-rewrite L1 staleness.
// ---------------------------------------------------------------------------

__device__ __forceinline__ void gbar(int* bar, int phase, int nblk) {
    __syncthreads();                 // drain this block's stores (vmcnt0@barrier)
    if (threadIdx.x == 0) {
        __threadfence();             // release: L2 writeback to L3 (cross-XCD)
        __hip_atomic_fetch_add(&bar[phase], 1, __ATOMIC_ACQ_REL,
                               __HIP_MEMORY_SCOPE_AGENT);
        while (__hip_atomic_load(&bar[phase], __ATOMIC_ACQUIRE,
                                 __HIP_MEMORY_SCOPE_AGENT) < nblk) {}
        __threadfence();             // acquire: invalidate stale L1/L2 lines
    }
    __syncthreads();
}

// R7-verified gather for one row: LDS-broadcast indices, 8 feature loads in
// flight per lane, clamp-to-row-0 + select multiplier for the tail.
__device__ __forceinline__ void gath_row(
    const float4* __restrict__ g4, const int* __restrict__ sidx,
    const int* __restrict__ colidx, float* __restrict__ sA,
    int r, int beg, int end, float idg, int ebeg, int cnt_e, int c8) {
    const int deg = end - beg;
    const int beg_l = beg - ebeg;
    float4 accA = {0.f, 0.f, 0.f, 0.f};
    float4 accB = {0.f, 0.f, 0.f, 0.f};
    if (cnt_e <= SIDX) {
        for (int t0 = 0; t0 < deg; t0 += 8) {
            float4 vv[8]; float sel[8];
            #pragma unroll
            for (int k = 0; k < 8; ++k) {
                const int li = beg_l + t0 + k;
                const bool p = (t0 + k) < deg;
                sel[k] = p ? 1.0f : 0.0f;
                const int safe = p ? sidx[li] : 0;
                vv[k] = g4[(size_t)safe * 8 + c8];
            }
            #pragma unroll
            for (int k = 0; k < 8; ++k) {
                const _Float16* hp = (const _Float16*)&vv[k];
                accA.x += sel[k] * (float)hp[0];
                accA.y += sel[k] * (float)hp[1];
                accA.z += sel[k] * (float)hp[2];
                accA.w += sel[k] * (float)hp[3];
                accB.x += sel[k] * (float)hp[4];
                accB.y += sel[k] * (float)hp[5];
                accB.z += sel[k] * (float)hp[6];
                accB.w += sel[k] * (float)hp[7];
            }
        }
    } else {
        for (int t0 = 0; t0 < deg; t0 += 8) {
            float4 vv[8]; float sel[8];
            #pragma unroll
            for (int k = 0; k < 8; ++k) {
                const int li = beg_l + t0 + k;
                const bool p = (t0 + k) < deg;
                sel[k] = p ? 1.0f : 0.0f;
                const int safe = p ? colidx[ebeg + li] : 0;
                vv[k] = g4[(size_t)safe * 8 + c8];
            }
            #pragma unroll
            for (int k = 0; k < 8; ++k) {
                const _Float16* hp = (const _Float16*)&vv[k];
                accA.x += sel[k] * (float)hp[0];
                accA.y += sel[k] * (float)hp[1];
                accA.z += sel[k] * (float)hp[2];
                accA.w += sel[k] * (float)hp[3];
                accB.x += sel[k] * (float)hp[4];
                accB.y += sel[k] * (float)hp[5];
                accB.z += sel[k] * (float)hp[6];
                accB.w += sel[k] * (float)hp[7];
            }
        }
    }
    float4 oA = {accA.x * idg, accA.y * idg, accA.z * idg, accA.w * idg};
    float4 oB = {accB.x * idg, accB.y * idg, accB.z * idg, accB.w * idg};
    *(float4*)(sA + r * 68 + c8 * 8 + 0) = oA;
    *(float4*)(sA + r * 68 + c8 * 8 + 4) = oB;
}

#define FMA4(acc, am, b0, b1, b2, b3)                                  \
    acc.x += am.x * b0.x + am.y * b1.x + am.z * b2.x + am.w * b3.x;    \
    acc.y += am.x * b0.y + am.y * b1.y + am.z * b2.y + am.w * b3.y;    \
    acc.z += am.x * b0.z + am.y * b1.z + am.z * b2.z + am.w * b3.z;    \
    acc.w += am.x * b0.w + am.y * b1.w + am.z * b2.w + am.w * b3.w;

#define LEAKY4(A)                                   \
    A.x = (A.x > 0.f) ? A.x : SLOPE * A.x;          \
    A.y = (A.y > 0.f) ? A.y : SLOPE * A.y;          \
    A.z = (A.z > 0.f) ? A.z : SLOPE * A.z;          \
    A.w = (A.w > 0.f) ? A.w : SLOPE * A.w;

#define PHASE_B(WL, BL, WR)                                                 \
    const int r0 = t & 15;                                                  \
    const int jq = t >> 4;                                                  \
    const int j0 = jq * 4;                                                  \
    const float4* __restrict__ Wl4 = (const float4*)(WL);                   \
    const float4* __restrict__ Wr4 = (const float4*)(WR);                   \
    const float4 bias = *(const float4*)((BL) + j0);                        \
    float4 acc0 = bias, acc1 = bias, acc2 = bias, acc3 = bias;              \
    _Pragma("unroll 2")                                                     \
    for (int k4 = 0; k4 < 16; ++k4) {                                       \
        float4 b0 = Wl4[(4 * k4 + 0) * 16 + jq];                            \
        float4 b1 = Wl4[(4 * k4 + 1) * 16 + jq];                            \
        float4 b2 = Wl4[(4 * k4 + 2) * 16 + jq];                            \
        float4 b3 = Wl4[(4 * k4 + 3) * 16 + jq];                            \
        float4 a0 = *(const float4*)(sA + (r0 +  0) * 68 + 4 * k4);         \
        float4 a1 = *(const float4*)(sA + (r0 + 16) * 68 + 4 * k4);         \
        float4 a2 = *(const float4*)(sA + (r0 + 32) * 68 + 4 * k4);         \
        float4 a3 = *(const float4*)(sA + (r0 + 48) * 68 + 4 * k4);         \
        FMA4(acc0, a0, b0, b1, b2, b3)                                      \
        FMA4(acc1, a1, b0, b1, b2, b3)                                      \
        FMA4(acc2, a2, b0, b1, b2, b3)                                      \
        FMA4(acc3, a3, b0, b1, b2, b3)                                      \
        b0 = Wr4[(4 * k4 + 0) * 16 + jq];                                   \
        b1 = Wr4[(4 * k4 + 1) * 16 + jq];                                   \
        b2 = Wr4[(4 * k4 + 2) * 16 + jq];                                   \
        b3 = Wr4[(4 * k4 + 3) * 16 + jq];                                   \
        a0 = *(const float4*)(sS + (r0 +  0) * 68 + 4 * k4);                \
        a1 = *(const float4*)(sS + (r0 + 16) * 68 + 4 * k4);                \
        a2 = *(const float4*)(sS + (r0 + 32) * 68 + 4 * k4);                \
        a3 = *(const float4*)(sS + (r0 + 48) * 68 + 4 * k4);                \
        FMA4(acc0, a0, b0, b1, b2, b3)                                      \
        FMA4(acc1, a1, b0, b1, b2, b3)                                      \
        FMA4(acc2, a2, b0, b1, b2, b3)                                      \
        FMA4(acc3, a3, b0, b1, b2, b3)                                      \
    }                                                                       \
    LEAKY4(acc0) LEAKY4(acc1) LEAKY4(acc2) LEAKY4(acc3)

// non-last layers: persist f32 h in sS AND write fp16 h coalesced to global
#define STORE_H(H16OUT)                                                     \
    __syncthreads();            /* phase-B sS reads done before overwrite */ \
    *(float4*)(sS + (r0 +  0) * 68 + j0) = acc0;                            \
    *(float4*)(sS + (r0 + 16) * 68 + j0) = acc1;                            \
    *(float4*)(sS + (r0 + 32) * 68 + j0) = acc2;                            \
    *(float4*)(sS + (r0 + 48) * 68 + j0) = acc3;                            \
    __syncthreads();                                                        \
    _Pragma("unroll")                                                       \
    for (int idx = 0; idx < 2; ++idx) {                                     \
        int i = t + idx * 256;                                              \
        int r = i >> 3, cc = i & 7;                                         \
        if (r < rows) {                                                     \
            float4 lo = *(const float4*)(sS + r * 68 + cc * 8 + 0);         \
            float4 hi = *(const float4*)(sS + r * 68 + cc * 8 + 4);         \
            _Float16 o[8] = {(_Float16)lo.x, (_Float16)lo.y,                \
                             (_Float16)lo.z, (_Float16)lo.w,                \
                             (_Float16)hi.x, (_Float16)hi.y,                \
                             (_Float16)hi.z, (_Float16)hi.w};               \
            *(float4*)((H16OUT) + (size_t)(base + r) * HD + cc * 8)         \
                = *(float4*)o;                                              \
        }                                                                   \
    }

__global__ __launch_bounds__(256, 4) void sage3_kernel(
    const int* __restrict__ ei, const float* __restrict__ x,
    _Float16* __restrict__ h16a, _Float16* __restrict__ h16b,
    _Float16* __restrict__ h16c,
    int* __restrict__ ebuf, int* __restrict__ colidx,
    int* __restrict__ rowptr, int* __restrict__ rowend,
    float* __restrict__ invdeg, int* __restrict__ bcur, int* __restrict__ bar,
    const float* __restrict__ Wl1, const float* __restrict__ bl1,
    const float* __restrict__ Wr1,
    const float* __restrict__ Wl2, const float* __restrict__ bl2,
    const float* __restrict__ Wr2,
    const float* __restrict__ Wl3, const float* __restrict__ bl3,
    const float* __restrict__ Wr3,
    const float* __restrict__ Wout, const float* __restrict__ bout,
    float* __restrict__ out, int N, int E, int nblk, int n64) {

    __shared__ int smem[9984];        // 39936 B -> exactly 4 blocks/CU
    const int t = threadIdx.x;

    // ============ phase P: edge partition (blocks with c0 < E) ============
    {
        int* pk_s  = smem;            // [4096]
        int* mt_s  = smem + 4096;     // [4096]
        int* hist  = smem + 8192;     // [784]
        int* sbase = smem + 8976;     // [784] (ends 9760 <= 9984)
        const int c0 = blockIdx.x * CHUNK;
        if (c0 < E) {
            const int cnt = min(CHUNK, E - c0);
            for (int i = t; i < nblk; i += 256) hist[i] = 0;
            __syncthreads();
            for (int i = t; i < cnt; i += 256) {
                int src = ei[c0 + i];
                int dst = ei[E + c0 + i];
                int b = dst >> BSH;
                pk_s[i] = (src << BSH) | (dst & (BNODES - 1));
                int r = atomicAdd(&hist[b], 1);
                mt_s[i] = (b << 12) | r;          // rank < CHUNK = 2^12
            }
            __syncthreads();
            for (int b = t; b < nblk; b += 256) {
                int h = hist[b];
                if (h) sbase[b] = b * SLOT + atomicAdd(&bcur[b], h);
            }
            __syncthreads();
            for (int i = t; i < cnt; i += 256) {
                int m = mt_s[i];
                int b = m >> 12;
                ebuf[sbase[b] + (m & (CHUNK - 1))] = pk_s[i];
            }
        }
    }
    gbar(bar, 0, nblk);

    // ============ phase S: per-bucket counting sort + x->fp16 ============
    {
        int* cntl = smem;             // [64]
        const int b = blockIdx.x;
        const int ebeg_s = b * SLOT;
        const int eend = ebeg_s + bcur[b];
        if (t < BNODES) cntl[t] = 0;
        __syncthreads();
        for (int k = ebeg_s + t; k < eend; k += 256)
            atomicAdd(&cntl[ebuf[k] & (BNODES - 1)], 1);
        __syncthreads();
        if (t < BNODES) {                     // wave 0: scan 64 counters
            int v = cntl[t];
            int x2 = v;
            #pragma unroll
            for (int d = 1; d < 64; d <<= 1) {
                int y = __shfl_up(x2, d, 64);
                if (t >= d) x2 += y;
            }
            int excl = x2 - v;
            int node = b * BNODES + t;
            if (node < N) {
                rowptr[node] = ebeg_s + excl;
                rowend[node] = ebeg_s + excl + v;
                invdeg[node] = 1.0f / (float)((v > 1) ? v : 1);
            }
            cntl[t] = excl;
        }
        __syncthreads();
        for (int k = ebeg_s + t; k < eend; k += 256) {
            int p = ebuf[k];
            int r = atomicAdd(&cntl[p & (BNODES - 1)], 1);
            colidx[ebeg_s + r] = p >> BSH;
        }
        // folded tohalf: x (f32) -> h16a
        const int total8 = n64 >> 3;
        for (int i = b * 256 + t; i < total8; i += nblk * 256) {
            int e = i * 8;
            float4 a = *(const float4*)(x + e);
            float4 c = *(const float4*)(x + e + 4);
            _Float16 o[8] = {(_Float16)a.x, (_Float16)a.y, (_Float16)a.z,
                             (_Float16)a.w, (_Float16)c.x, (_Float16)c.y,
                             (_Float16)c.z, (_Float16)c.w};
            *(float4*)(h16a + e) = *(float4*)o;
        }
    }
    gbar(bar, 1, nblk);

    // ============ layer setup (once) ============
    float* sA  = (float*)smem;            // [64*68] f32
    float* sS  = (float*)(smem + 4352);   // [64*68] f32
    int* sidx  = smem + 8704;             // [1280]
    const int base = blockIdx.x * 64;
    const int rows = min(64, N - base);
    const int ebeg = blockIdx.x * SLOT;
    const int cnt_e = bcur[blockIdx.x];
    {   // stage sidx once (layer-invariant)
        const int cs = min(cnt_e, SIDX);
        for (int i = t; i < cs; i += 256) sidx[i] = colidx[ebeg + i];
    }
    {   // stage self tile from h16a into sS (f32)
        #pragma unroll
        for (int idx = 0; idx < 2; ++idx) {
            int i = t + idx * 256;
            int r = i >> 3, cc = i & 7;
            float4 raw = {0.f, 0.f, 0.f, 0.f};
            if (r < rows) raw = ((const float4*)h16a)[(size_t)(base + r) * 8 + cc];
            const _Float16* hp = (const _Float16*)&raw;
            float4 lo = {(float)hp[0], (float)hp[1], (float)hp[2], (float)hp[3]};
            float4 hi = {(float)hp[4], (float)hp[5], (float)hp[6], (float)hp[7]};
            *(float4*)(sS + r * 68 + cc * 8 + 0) = lo;
            *(float4*)(sS + r * 68 + cc * 8 + 4) = hi;
        }
    }
    const int lane = t & 63;
    const int w = t >> 6;
    const int g = lane >> 3;
    const int c8 = lane & 7;
    const int rA0 = w * 16 + g;           // pass-0 row
    const int rA1 = rA0 + 8;              // pass-1 row
    int beg0 = 0, end0 = 0; float idg0 = 0.f;
    if (base + rA0 < N) {
        beg0 = rowptr[base + rA0]; end0 = rowend[base + rA0];
        idg0 = invdeg[base + rA0];
    }
    int beg1 = 0, end1 = 0; float idg1 = 0.f;
    if (base + rA1 < N) {
        beg1 = rowptr[base + rA1]; end1 = rowend[base + rA1];
        idg1 = invdeg[base + rA1];
    }
    __syncthreads();                      // sidx + sS ready

    const float4* g4a = (const float4*)h16a;
    const float4* g4b = (const float4*)h16b;
    const float4* g4c = (const float4*)h16c;

    // ============ layer 1 ============
    {
        gath_row(g4a, sidx, colidx, sA, rA0, beg0, end0, idg0, ebeg, cnt_e, c8);
        gath_row(g4a, sidx, colidx, sA, rA1, beg1, end1, idg1, ebeg, cnt_e, c8);
        __syncthreads();
        PHASE_B(Wl1, bl1, Wr1)
        STORE_H(h16b)
    }
    gbar(bar, 2, nblk);

    // ============ layer 2 ============
    {
        gath_row(g4b, sidx, colidx, sA, rA0, beg0, end0, idg0, ebeg, cnt_e, c8);
        gath_row(g4b, sidx, colidx, sA, rA1, beg1, end1, idg1, ebeg, cnt_e, c8);
        __syncthreads();
        PHASE_B(Wl2, bl2, Wr2)
        STORE_H(h16c)
    }
    gbar(bar, 3, nblk);

    // ============ layer 3 + output head ============
    {
        gath_row(g4c, sidx, colidx, sA, rA0, beg0, end0, idg0, ebeg, cnt_e, c8);
        gath_row(g4c, sidx, colidx, sA, rA1, beg1, end1, idg1, ebeg, cnt_e, c8);
        __syncthreads();
        PHASE_B(Wl3, bl3, Wr3)
        float* s_part = (float*)sidx;     // sidx dead after phase A
        const float4 w4 = *(const float4*)(Wout + j0);
        s_part[jq * 64 + r0 +  0] = acc0.x * w4.x + acc0.y * w4.y + acc0.z * w4.z + acc0.w * w4.w;
        s_part[jq * 64 + r0 + 16] = acc1.x * w4.x + acc1.y * w4.y + acc1.z * w4.z + acc1.w * w4.w;
        s_part[jq * 64 + r0 + 32] = acc2.x * w4.x + acc2.y * w4.y + acc2.z * w4.z + acc2.w * w4.w;
        s_part[jq * 64 + r0 + 48] = acc3.x * w4.x + acc3.y * w4.y + acc3.z * w4.z + acc3.w * w4.w;
        __syncthreads();
        if (t < 64) {
            float sum = 0.f;
            #pragma unroll
            for (int g2 = 0; g2 < 16; ++g2) sum += s_part[g2 * 64 + t];
            if (t < rows) out[base + t] = sum + bout[0];
        }
    }
}

// ---------------------------------------------------------------------------

extern "C" void kernel_launch(void* const* d_in, const int* in_sizes, int n_in,
                              void* d_out, int out_size, void* d_ws, size_t ws_size,
                              hipStream_t stream) {
    const float* x   = (const float*)d_in[0];
    const int* ei    = (const int*)d_in[1];
    const float* Wl1 = (const float*)d_in[2];
    const float* bl1 = (const float*)d_in[3];
    const float* Wr1 = (const float*)d_in[4];
    const float* Wl2 = (const float*)d_in[5];
    const float* bl2 = (const float*)d_in[6];
    const float* Wr2 = (const float*)d_in[7];
    const float* Wl3 = (const float*)d_in[8];
    const float* bl3 = (const float*)d_in[9];
    const float* Wr3 = (const float*)d_in[10];
    const float* Wout = (const float*)d_in[11];
    const float* bout = (const float*)d_in[12];
    float* out = (float*)d_out;

    const int N = in_sizes[0] / HD;       // 50000
    const int E = in_sizes[1] / 2;        // 800000
    const int NB = (N + BNODES - 1) >> BSH;   // 782 blocks == buckets == tiles
    const int n64 = N * HD;

    // Workspace layout — float4-accessed buffers first (16B alignment).
    _Float16* h16a = (_Float16*)d_ws;                // [N*64] f16
    _Float16* h16b = h16a + (size_t)N * HD;          // [N*64] f16
    _Float16* h16c = h16b + (size_t)N * HD;          // [N*64] f16
    int* ebuf     = (int*)(h16c + (size_t)N * HD);   // [NB*SLOT]
    int* colidx   = ebuf + (size_t)NB * SLOT;        // [NB*SLOT]
    int* rowptr   = colidx + (size_t)NB * SLOT;      // [N]
    int* rowend   = rowptr + N;                      // [N]
    float* invdeg = (float*)(rowend + N);            // [N]
    int* bcur     = (int*)(invdeg + N);              // [784]
    int* bar      = bcur + 784;                      // [4] barrier counters

    hipMemsetAsync(bcur, 0, 788 * sizeof(int), stream);   // bcur + bar

    sage3_kernel<<<NB, 256, 0, stream>>>(
        ei, x, h16a, h16b, h16c, ebuf, colidx, rowptr, rowend, invdeg,
        bcur, bar,
        Wl1, bl1, Wr1, Wl2, bl2, Wr2, Wl3, bl3, Wr3, Wout, bout,
        out, N, E, NB, n64);
}

// Round 12
// 242.973 us; speedup vs baseline: 3.7588x; 3.7588x over previous
//
#include <hip/hip_runtime.h>

#define HD 64
#define SLOPE 0.01f
#define BSH 6                    // 64 nodes per bucket
#define BNODES 64
#define CHUNK 4096               // edges per partition block
#define SLOT 1536                // padded edge capacity per bucket (exp max ~1150)
#define SIDX 1280                // LDS-staged colidx capacity (5KB)

// ---------------------------------------------------------------------------
// Build v4 (R13-proven): padded-slot partition -> per-bucket counting sort.
// (R2: scatter build = 16x write amp. R5: coop launch no-ops under capture.
//  R9: single-kernel fusion w/ software barrier = per-block agent fences
//  force full per-XCD L2 writeback/invalidate x3000 -> 873us. Fusion closed.)
// ---------------------------------------------------------------------------

__global__ __launch_bounds__(256) void part_kernel(const int* __restrict__ ei,
                                                   int* __restrict__ bcur,
                                                   int* __restrict__ ebuf,
                                                   int E, int nb) {
    __shared__ int pk_s[CHUNK];
    __shared__ int mt_s[CHUNK];
    __shared__ int hist[784];
    __shared__ int sbase[784];
    const int t = threadIdx.x;
    const int c0 = blockIdx.x * CHUNK;
    const int cnt = min(CHUNK, E - c0);
    for (int i = t; i < nb; i += 256) hist[i] = 0;
    __syncthreads();
    for (int i = t; i < cnt; i += 256) {
        int src = ei[c0 + i];
        int dst = ei[E + c0 + i];
        int b = dst >> BSH;
        pk_s[i] = (src << BSH) | (dst & (BNODES - 1));
        int r = atomicAdd(&hist[b], 1);
        mt_s[i] = (b << 12) | r;           // rank < CHUNK = 2^12
    }
    __syncthreads();
    for (int b = t; b < nb; b += 256) {
        int h = hist[b];
        if (h) sbase[b] = b * SLOT + atomicAdd(&bcur[b], h);   // padded slot
    }
    __syncthreads();
    for (int i = t; i < cnt; i += 256) {
        int m = mt_s[i];
        int b = m >> 12;
        ebuf[sbase[b] + (m & (CHUNK - 1))] = pk_s[i];
    }
}

__global__ __launch_bounds__(256) void bsort_kernel(const int* __restrict__ ebuf,
                                                    const int* __restrict__ bcnt,
                                                    int* __restrict__ colidx,
                                                    int* __restrict__ rowptr,
                                                    int* __restrict__ rowend,
                                                    float* __restrict__ invdeg,
                                                    const float* __restrict__ x,
                                                    _Float16* __restrict__ h16a,
                                                    int n, int n64) {
    __shared__ int cnt[BNODES];
    const int b = blockIdx.x;
    const int t = threadIdx.x;
    const int ebeg = b * SLOT;
    const int eend = ebeg + bcnt[b];
    if (t < BNODES) cnt[t] = 0;
    __syncthreads();
    for (int k = ebeg + t; k < eend; k += 256)
        atomicAdd(&cnt[ebuf[k] & (BNODES - 1)], 1);
    __syncthreads();
    if (t < BNODES) {                      // wave 0: scan the 64 counters
        int v = cnt[t];
        int x2 = v;
        #pragma unroll
        for (int d = 1; d < 64; d <<= 1) { int y = __shfl_up(x2, d, 64); if (t >= d) x2 += y; }
        int excl = x2 - v;
        int node = b * BNODES + t;
        if (node < n) {
            rowptr[node] = ebeg + excl;
            rowend[node] = ebeg + excl + v;
            invdeg[node] = 1.0f / (float)((v > 1) ? v : 1);
        }
        cnt[t] = excl;                     // becomes the running cursor
    }
    __syncthreads();
    for (int k = ebeg + t; k < eend; k += 256) {
        int p = ebuf[k];
        int r = atomicAdd(&cnt[p & (BNODES - 1)], 1);
        colidx[ebeg + r] = p >> BSH;
    }
    // --- folded tohalf: x (f32) -> h16a, grid-stride, 8 elems/iter ---
    const int total8 = n64 >> 3;
    for (int i = b * 256 + t; i < total8; i += gridDim.x * 256) {
        int e = i * 8;
        float4 a = *(const float4*)(x + e);
        float4 c = *(const float4*)(x + e + 4);
        _Float16 o[8] = {(_Float16)a.x, (_Float16)a.y, (_Float16)a.z, (_Float16)a.w,
                         (_Float16)c.x, (_Float16)c.y, (_Float16)c.z, (_Float16)c.w};
        *(float4*)(h16a + e) = *(float4*)o;
    }
}

// ---------------------------------------------------------------------------
// Fused SAGE layer v10 (R10): 512-thread blocks, SAME 64-node tile.
// LDS unchanged (39936B -> 4 blocks/CU) but now 4 x 8 = 32 waves/CU (2x
// latency hiding) and each wave runs ONE 8-row gather pass (chain halves,
// concurrent chains double). Per-block fixed costs unchanged — isolates the
// occupancy/MLP variable that R4 (fixed-cost confound) and R8 (spill) could
// not. Phase B: 2 rows/thread (r0 0..31). Per-(row,j) math identical.
// __launch_bounds__(512,8) targets the 64-VGPR budget R9's body already fit.
// ---------------------------------------------------------------------------

#define FMA4(acc, am, b0, b1, b2, b3)                                  \
    acc.x += am.x * b0.x + am.y * b1.x + am.z * b2.x + am.w * b3.x;    \
    acc.y += am.x * b0.y + am.y * b1.y + am.z * b2.y + am.w * b3.y;    \
    acc.z += am.x * b0.z + am.y * b1.z + am.z * b2.z + am.w * b3.z;    \
    acc.w += am.x * b0.w + am.y * b1.w + am.z * b2.w + am.w * b3.w;

#define GATHER_LOOP(IDX_EXPR)                                               \
    for (int t0 = 0; t0 < deg; t0 += 8) {                                   \
        float4 vv[8];                                                       \
        float sel[8];                                                       \
        _Pragma("unroll")                                                   \
        for (int k = 0; k < 8; ++k) {                                       \
            const int li = beg_l + t0 + k;                                  \
            const int cix = IDX_EXPR;                                       \
            const bool p = (t0 + k) < deg;                                  \
            sel[k] = p ? 1.0f : 0.0f;                                       \
            const int safe = p ? cix : 0;                                   \
            vv[k] = g4[(size_t)safe * 8 + c8];                              \
        }                                                                   \
        _Pragma("unroll")                                                   \
        for (int k = 0; k < 8; ++k) {                                       \
            const _Float16* hp = (const _Float16*)&vv[k];                   \
            accA.x += sel[k] * (float)hp[0];                                \
            accA.y += sel[k] * (float)hp[1];                                \
            accA.z += sel[k] * (float)hp[2];                                \
            accA.w += sel[k] * (float)hp[3];                                \
            accB.x += sel[k] * (float)hp[4];                                \
            accB.y += sel[k] * (float)hp[5];                                \
            accB.z += sel[k] * (float)hp[6];                                \
            accB.w += sel[k] * (float)hp[7];                                \
        }                                                                   \
    }

#define FUSED_BODY(EXTRA_SHARED)                                            \
    __shared__ float sA[64 * 68];     /* mean tile, f32, stride 68 */       \
    __shared__ float sS[64 * 68];     /* self tile, f32 */                  \
    __shared__ int sidx[SIDX];        /* staged colidx window, 5KB */       \
    EXTRA_SHARED                                                            \
    const int t = threadIdx.x;                                              \
    const int lane = t & 63;                                                \
    const int w = t >> 6;             /* wave 0..7 */                       \
    const int base = blockIdx.x * 64;                                       \
    const int rows = min(64, n - base);                                     \
    const int ebeg = blockIdx.x * SLOT;                                     \
    const float4* __restrict__ g4 = (const float4*)h16_in;                  \
    /* stage this block's colidx window into LDS (coalesced) */             \
    const int cnt_e = rowend[base + rows - 1] - ebeg;                       \
    {                                                                       \
        const int cnt_s = min(cnt_e, SIDX);                                 \
        for (int i = t; i < cnt_s; i += 512) sidx[i] = colidx[ebeg + i];    \
    }                                                                       \
    /* stage self tile from fp16: 512 threads cover 64 rows x 8 chunks */   \
    {                                                                       \
        int r = t >> 3, cc = t & 7;                                         \
        float4 raw = {0.f, 0.f, 0.f, 0.f};                                  \
        if (r < rows) raw = g4[(size_t)(base + r) * 8 + cc];                \
        const _Float16* hp = (const _Float16*)&raw;                         \
        float4 lo = {(float)hp[0], (float)hp[1], (float)hp[2], (float)hp[3]}; \
        float4 hi = {(float)hp[4], (float)hp[5], (float)hp[6], (float)hp[7]}; \
        *(float4*)(sS + r * 68 + cc * 8 + 0) = lo;                          \
        *(float4*)(sS + r * 68 + cc * 8 + 4) = hi;                          \
    }                                                                       \
    __syncthreads();                  /* sidx ready for phase A */          \
    /* ---- phase A: each wave ONE 8-row pass ---- */                       \
    {                                                                       \
        const int g = lane >> 3;      /* node slot 0..7 */                  \
        const int c8 = lane & 7;      /* 16B chunk of 128B fp16 row */      \
        const int r = w * 8 + g;      /* local row 0..63 */                 \
        const int node = base + r;                                          \
        const bool valid = node < n;                                        \
        int beg = 0, end = 0; float idg = 0.f;                              \
        if (valid) {                                                        \
            beg = rowptr[node];                                             \
            end = rowend[node];                                             \
            idg = invdeg[node];                                             \
        }                                                                   \
        const int deg = end - beg;                                          \
        const int beg_l = beg - ebeg;                                       \
        float4 accA = {0.f, 0.f, 0.f, 0.f};                                 \
        float4 accB = {0.f, 0.f, 0.f, 0.f};                                 \
        if (cnt_e <= SIDX) {                                                \
            GATHER_LOOP(sidx[li])                                           \
        } else {                                                            \
            GATHER_LOOP(colidx[ebeg + li])                                  \
        }                                                                   \
        float4 oA = {accA.x * idg, accA.y * idg, accA.z * idg, accA.w * idg}; \
        float4 oB = {accB.x * idg, accB.y * idg, accB.z * idg, accB.w * idg}; \
        *(float4*)(sA + r * 68 + c8 * 8 + 0) = oA;                          \
        *(float4*)(sA + r * 68 + c8 * 8 + 4) = oB;                          \
    }                                                                       \
    __syncthreads();                                                        \
    /* ---- phase B: 512 threads, 2 rows/thread, W from global ---- */      \
    const int r0 = t & 31;            /* rows r0, r0+32 */                  \
    const int jq = t >> 5;            /* j0/4, 0..15 */                     \
    const int j0 = jq * 4;                                                  \
    const float4* __restrict__ Wl4 = (const float4*)Wl;                     \
    const float4* __restrict__ Wr4 = (const float4*)Wr;                     \
    const float4 bias = *(const float4*)(bl + j0);                          \
    float4 acc0 = bias, acc1 = bias;                                        \
    _Pragma("unroll 2")                                                     \
    for (int k4 = 0; k4 < 16; ++k4) {                                       \
        float4 b0 = Wl4[(4 * k4 + 0) * 16 + jq];                            \
        float4 b1 = Wl4[(4 * k4 + 1) * 16 + jq];                            \
        float4 b2 = Wl4[(4 * k4 + 2) * 16 + jq];                            \
        float4 b3 = Wl4[(4 * k4 + 3) * 16 + jq];                            \
        float4 a0 = *(const float4*)(sA + (r0 +  0) * 68 + 4 * k4);         \
        float4 a1 = *(const float4*)(sA + (r0 + 32) * 68 + 4 * k4);         \
        FMA4(acc0, a0, b0, b1, b2, b3)                                      \
        FMA4(acc1, a1, b0, b1, b2, b3)                                      \
        b0 = Wr4[(4 * k4 + 0) * 16 + jq];                                   \
        b1 = Wr4[(4 * k4 + 1) * 16 + jq];                                   \
        b2 = Wr4[(4 * k4 + 2) * 16 + jq];                                   \
        b3 = Wr4[(4 * k4 + 3) * 16 + jq];                                   \
        a0 = *(const float4*)(sS + (r0 +  0) * 68 + 4 * k4);                \
        a1 = *(const float4*)(sS + (r0 + 32) * 68 + 4 * k4);                \
        FMA4(acc0, a0, b0, b1, b2, b3)                                      \
        FMA4(acc1, a1, b0, b1, b2, b3)                                      \
    }                                                                       \
    acc0.x = (acc0.x > 0.f) ? acc0.x : SLOPE * acc0.x;                      \
    acc0.y = (acc0.y > 0.f) ? acc0.y : SLOPE * acc0.y;                      \
    acc0.z = (acc0.z > 0.f) ? acc0.z : SLOPE * acc0.z;                      \
    acc0.w = (acc0.w > 0.f) ? acc0.w : SLOPE * acc0.w;                      \
    acc1.x = (acc1.x > 0.f) ? acc1.x : SLOPE * acc1.x;                      \
    acc1.y = (acc1.y > 0.f) ? acc1.y : SLOPE * acc1.y;                      \
    acc1.z = (acc1.z > 0.f) ? acc1.z : SLOPE * acc1.z;                      \
    acc1.w = (acc1.w > 0.f) ? acc1.w : SLOPE * acc1.w;

__global__ __launch_bounds__(512, 8) void sage_fused(
    const _Float16* __restrict__ h16_in, _Float16* __restrict__ h16_out,
    const int* __restrict__ rowptr, const int* __restrict__ rowend,
    const int* __restrict__ colidx, const float* __restrict__ invdeg,
    const float* __restrict__ Wl, const float* __restrict__ bl,
    const float* __restrict__ Wr, int n) {
    FUSED_BODY()
    // ---- coalesced epilogue: accs -> sA (dead) -> fp16 global ----
    __syncthreads();            // all phase-B sA reads done before overwrite
    *(float4*)(sA + (r0 +  0) * 68 + j0) = acc0;
    *(float4*)(sA + (r0 + 32) * 68 + j0) = acc1;
    __syncthreads();
    {
        int r = t >> 3, cc = t & 7;       // 512 threads = 64 rows x 8 chunks
        if (r < rows) {
            float4 lo = *(const float4*)(sA + r * 68 + cc * 8 + 0);
            float4 hi = *(const float4*)(sA + r * 68 + cc * 8 + 4);
            _Float16 o[8] = {(_Float16)lo.x, (_Float16)lo.y,
                             (_Float16)lo.z, (_Float16)lo.w,
                             (_Float16)hi.x, (_Float16)hi.y,
                             (_Float16)hi.z, (_Float16)hi.w};
            *(float4*)(h16_out + (size_t)(base + r) * HD + cc * 8) = *(float4*)o;
        }
    }
}

// Layer-3 variant: h3 never hits memory — dot with Wout, cross-wave LDS
// reduction, write out[node] (f32) directly. s_part aliases the dead sidx.
__global__ __launch_bounds__(512, 8) void sage_fused_out(
    const _Float16* __restrict__ h16_in,
    const int* __restrict__ rowptr, const int* __restrict__ rowend,
    const int* __restrict__ colidx, const float* __restrict__ invdeg,
    const float* __restrict__ Wl, const float* __restrict__ bl,
    const float* __restrict__ Wr,
    const float* __restrict__ Wout, const float* __restrict__ bout,
    float* __restrict__ out, int n) {
    FUSED_BODY()
    float* s_part = (float*)sidx;     // [16][64] alias, sidx dead here
    const float4 w4 = *(const float4*)(Wout + j0);
    s_part[jq * 64 + r0 +  0] = acc0.x * w4.x + acc0.y * w4.y + acc0.z * w4.z + acc0.w * w4.w;
    s_part[jq * 64 + r0 + 32] = acc1.x * w4.x + acc1.y * w4.y + acc1.z * w4.z + acc1.w * w4.w;
    __syncthreads();
    if (t < 64) {
        float sum = 0.f;
        #pragma unroll
        for (int g2 = 0; g2 < 16; ++g2) sum += s_part[g2 * 64 + t];
        if (t < rows) out[base + t] = sum + bout[0];
    }
}

// ---------------------------------------------------------------------------

extern "C" void kernel_launch(void* const* d_in, const int* in_sizes, int n_in,
                              void* d_out, int out_size, void* d_ws, size_t ws_size,
                              hipStream_t stream) {
    const float* x   = (const float*)d_in[0];
    const int* ei    = (const int*)d_in[1];
    const float* Wl1 = (const float*)d_in[2];
    const float* bl1 = (const float*)d_in[3];
    const float* Wr1 = (const float*)d_in[4];
    const float* Wl2 = (const float*)d_in[5];
    const float* bl2 = (const float*)d_in[6];
    const float* Wr2 = (const float*)d_in[7];
    const float* Wl3 = (const float*)d_in[8];
    const float* bl3 = (const float*)d_in[9];
    const float* Wr3 = (const float*)d_in[10];
    const float* Wout = (const float*)d_in[11];
    const float* bout = (const float*)d_in[12];
    float* out = (float*)d_out;

    const int N = in_sizes[0] / HD;       // 50000
    const int E = in_sizes[1] / 2;        // 800000
    const int NB = (N + BNODES - 1) >> BSH;   // 782 buckets
    const int n64 = N * HD;

    // Workspace layout — float4-accessed buffers first (16B alignment).
    _Float16* h16a = (_Float16*)d_ws;                // [N*64] f16
    _Float16* h16b = h16a + (size_t)N * HD;          // [N*64] f16
    int* ebuf     = (int*)(h16b + (size_t)N * HD);   // [NB*SLOT] packed edges
    int* colidx   = ebuf + (size_t)NB * SLOT;        // [NB*SLOT] padded CSR
    int* rowptr   = colidx + (size_t)NB * SLOT;      // [N]
    int* rowend   = rowptr + N;                      // [N]
    float* invdeg = (float*)(rowend + N);            // [N]
    int* bcur     = (int*)(invdeg + N);              // [784]

    hipMemsetAsync(bcur, 0, 784 * sizeof(int), stream);

    part_kernel<<<(E + CHUNK - 1) / CHUNK, 256, 0, stream>>>(ei, bcur, ebuf, E, NB);
    bsort_kernel<<<NB, 256, 0, stream>>>(ebuf, bcur, colidx, rowptr, rowend,
                                         invdeg, x, h16a, N, n64);

    const int ggrid = (N + 63) / 64;      // 782 tiles

    sage_fused<<<ggrid, 512, 0, stream>>>(h16a, h16b,
                                          rowptr, rowend, colidx, invdeg,
                                          Wl1, bl1, Wr1, N);
    sage_fused<<<ggrid, 512, 0, stream>>>(h16b, h16a,
                                          rowptr, rowend, colidx, invdeg,
                                          Wl2, bl2, Wr2, N);
    sage_fused_out<<<ggrid, 512, 0, stream>>>(h16a,
                                              rowptr, rowend, colidx, invdeg,
                                              Wl3, bl3, Wr3, Wout, bout, out, N);
}

// Round 13
// 202.126 us; speedup vs baseline: 4.5184x; 1.2021x over previous
//
#include <hip/hip_runtime.h>

#define HD 64
#define SLOPE 0.01f
#define BSH 6                    // 64 nodes per bucket
#define BNODES 64
#define CHUNK 4096               // edges per partition block
#define SLOT 1536                // padded edge capacity per bucket (exp max ~1150)
#define SIDX 1280                // LDS-staged colidx capacity (5KB)

// ---------------------------------------------------------------------------
// Build v5 (R13): part_kernel folds the x->fp16 convert (independent work;
// part only has 196 blocks so 60+ CUs were idle). bsort sheds its tail.
// (R2: scatter build = 16x write amp. R5: coop launch no-ops under capture.
//  R9: sw-barrier fusion = per-block agent fences -> 873us. Fusion closed.
//  R12: 2x occupancy = null -> layer is bound by random-gather fill path,
//  ~0.8TB/s on 34MB/layer L2-miss traffic. 256-thr/64-tile is the optimum.)
// ---------------------------------------------------------------------------

__global__ __launch_bounds__(256) void part_kernel(const int* __restrict__ ei,
                                                   int* __restrict__ bcur,
                                                   int* __restrict__ ebuf,
                                                   const float* __restrict__ x,
                                                   _Float16* __restrict__ h16a,
                                                   int E, int nb, int n64) {
    __shared__ int pk_s[CHUNK];
    __shared__ int mt_s[CHUNK];
    __shared__ int hist[784];
    __shared__ int sbase[784];
    const int t = threadIdx.x;
    const int c0 = blockIdx.x * CHUNK;
    const int cnt = min(CHUNK, E - c0);
    for (int i = t; i < nb; i += 256) hist[i] = 0;
    __syncthreads();
    for (int i = t; i < cnt; i += 256) {
        int src = ei[c0 + i];
        int dst = ei[E + c0 + i];
        int b = dst >> BSH;
        pk_s[i] = (src << BSH) | (dst & (BNODES - 1));
        int r = atomicAdd(&hist[b], 1);
        mt_s[i] = (b << 12) | r;           // rank < CHUNK = 2^12
    }
    __syncthreads();
    for (int b = t; b < nb; b += 256) {
        int h = hist[b];
        if (h) sbase[b] = b * SLOT + atomicAdd(&bcur[b], h);   // padded slot
    }
    __syncthreads();
    for (int i = t; i < cnt; i += 256) {
        int m = mt_s[i];
        int b = m >> 12;
        ebuf[sbase[b] + (m & (CHUNK - 1))] = pk_s[i];
    }
    // --- folded tohalf: x (f32) -> h16a, grid-stride, 8 elems/iter ---
    const int total8 = n64 >> 3;
    for (int i = blockIdx.x * 256 + t; i < total8; i += gridDim.x * 256) {
        int e = i * 8;
        float4 a = *(const float4*)(x + e);
        float4 c = *(const float4*)(x + e + 4);
        _Float16 o[8] = {(_Float16)a.x, (_Float16)a.y, (_Float16)a.z, (_Float16)a.w,
                         (_Float16)c.x, (_Float16)c.y, (_Float16)c.z, (_Float16)c.w};
        *(float4*)(h16a + e) = *(float4*)o;
    }
}

__global__ __launch_bounds__(256) void bsort_kernel(const int* __restrict__ ebuf,
                                                    const int* __restrict__ bcnt,
                                                    int* __restrict__ colidx,
                                                    int* __restrict__ rowptr,
                                                    int* __restrict__ rowend,
                                                    float* __restrict__ invdeg,
                                                    int n) {
    __shared__ int cnt[BNODES];
    const int b = blockIdx.x;
    const int t = threadIdx.x;
    const int ebeg = b * SLOT;
    const int eend = ebeg + bcnt[b];
    if (t < BNODES) cnt[t] = 0;
    __syncthreads();
    for (int k = ebeg + t; k < eend; k += 256)
        atomicAdd(&cnt[ebuf[k] & (BNODES - 1)], 1);
    __syncthreads();
    if (t < BNODES) {                      // wave 0: scan the 64 counters
        int v = cnt[t];
        int x2 = v;
        #pragma unroll
        for (int d = 1; d < 64; d <<= 1) { int y = __shfl_up(x2, d, 64); if (t >= d) x2 += y; }
        int excl = x2 - v;
        int node = b * BNODES + t;
        if (node < n) {
            rowptr[node] = ebeg + excl;
            rowend[node] = ebeg + excl + v;
            invdeg[node] = 1.0f / (float)((v > 1) ? v : 1);
        }
        cnt[t] = excl;                     // becomes the running cursor
    }
    __syncthreads();
    for (int k = ebeg + t; k < eend; k += 256) {
        int p = ebuf[k];
        int r = atomicAdd(&cnt[p & (BNODES - 1)], 1);
        colidx[ebeg + r] = p >> BSH;
    }
}

// ---------------------------------------------------------------------------
// Fused SAGE layer v8 (R7-verified, 201.4us): LDS-staged colidx (indices as
// LDS broadcasts, zero shfls), per-group degree loop, coalesced epilogue.
// 256 threads / 64-node tile / 4 blocks/CU — R12 proved occupancy is not
// the lever; this config is the measured optimum.
// ---------------------------------------------------------------------------

#define FMA4(acc, am, b0, b1, b2, b3)                                  \
    acc.x += am.x * b0.x + am.y * b1.x + am.z * b2.x + am.w * b3.x;    \
    acc.y += am.x * b0.y + am.y * b1.y + am.z * b2.y + am.w * b3.y;    \
    acc.z += am.x * b0.z + am.y * b1.z + am.z * b2.z + am.w * b3.z;    \
    acc.w += am.x * b0.w + am.y * b1.w + am.z * b2.w + am.w * b3.w;

#define GATHER_LOOP(IDX_EXPR)                                               \
    for (int t0 = 0; t0 < deg; t0 += 8) {                                   \
        float4 vv[8];                                                       \
        float sel[8];                                                       \
        _Pragma("unroll")                                                   \
        for (int k = 0; k < 8; ++k) {                                       \
            const int li = beg_l + t0 + k;                                  \
            const int cix = IDX_EXPR;                                       \
            const bool p = (t0 + k) < deg;                                  \
            sel[k] = p ? 1.0f : 0.0f;                                       \
            const int safe = p ? cix : 0;                                   \
            vv[k] = g4[(size_t)safe * 8 + c8];                              \
        }                                                                   \
        _Pragma("unroll")                                                   \
        for (int k = 0; k < 8; ++k) {                                       \
            const _Float16* hp = (const _Float16*)&vv[k];                   \
            accA.x += sel[k] * (float)hp[0];                                \
            accA.y += sel[k] * (float)hp[1];                                \
            accA.z += sel[k] * (float)hp[2];                                \
            accA.w += sel[k] * (float)hp[3];                                \
            accB.x += sel[k] * (float)hp[4];                                \
            accB.y += sel[k] * (float)hp[5];                                \
            accB.z += sel[k] * (float)hp[6];                                \
            accB.w += sel[k] * (float)hp[7];                                \
        }                                                                   \
    }

#define FUSED_BODY(EXTRA_SHARED)                                            \
    __shared__ float sA[64 * 68];     /* mean tile, f32, stride 68 */       \
    __shared__ float sS[64 * 68];     /* self tile, f32 */                  \
    __shared__ int sidx[SIDX];        /* staged colidx window, 5KB */       \
    EXTRA_SHARED                                                            \
    const int t = threadIdx.x;                                              \
    const int lane = t & 63;                                                \
    const int w = t >> 6;                                                   \
    const int base = blockIdx.x * 64;                                       \
    const int rows = min(64, n - base);                                     \
    const int ebeg = blockIdx.x * SLOT;                                     \
    const float4* __restrict__ g4 = (const float4*)h16_in;                  \
    /* stage this block's colidx window into LDS (coalesced) */             \
    const int cnt_e = rowend[base + rows - 1] - ebeg;                       \
    {                                                                       \
        const int cnt_s = min(cnt_e, SIDX);                                 \
        for (int i = t; i < cnt_s; i += 256) sidx[i] = colidx[ebeg + i];    \
    }                                                                       \
    /* stage self tile from fp16 (8KB streaming read, convert to f32) */    \
    _Pragma("unroll")                                                       \
    for (int idx = 0; idx < 2; ++idx) {                                     \
        int i = t + idx * 256;            /* 0..511 */                      \
        int r = i >> 3, cc = i & 7;                                         \
        float4 raw = {0.f, 0.f, 0.f, 0.f};                                  \
        if (r < rows) raw = g4[(size_t)(base + r) * 8 + cc];                \
        const _Float16* hp = (const _Float16*)&raw;                         \
        float4 lo = {(float)hp[0], (float)hp[1], (float)hp[2], (float)hp[3]}; \
        float4 hi = {(float)hp[4], (float)hp[5], (float)hp[6], (float)hp[7]}; \
        *(float4*)(sS + r * 68 + cc * 8 + 0) = lo;                          \
        *(float4*)(sS + r * 68 + cc * 8 + 4) = hi;                          \
    }                                                                       \
    __syncthreads();                  /* sidx ready for phase A */          \
    /* ---- phase A: aggregate into sA ---- */                              \
    {                                                                       \
        const int g = lane >> 3;      /* node slot 0..7 */                  \
        const int c8 = lane & 7;      /* 16B chunk of 128B fp16 row */      \
        _Pragma("unroll")                                                   \
        for (int pass = 0; pass < 2; ++pass) {                              \
            const int r = w * 16 + pass * 8 + g;   /* local row 0..63 */    \
            const int node = base + r;                                      \
            const bool valid = node < n;                                    \
            int beg = 0, end = 0; float idg = 0.f;                          \
            if (valid) {                                                    \
                beg = rowptr[node];                                         \
                end = rowend[node];                                         \
                idg = invdeg[node];                                         \
            }                                                               \
            const int deg = end - beg;                                      \
            const int beg_l = beg - ebeg;                                   \
            float4 accA = {0.f, 0.f, 0.f, 0.f};                             \
            float4 accB = {0.f, 0.f, 0.f, 0.f};                             \
            if (cnt_e <= SIDX) {                                            \
                GATHER_LOOP(sidx[li])                                       \
            } else {                                                        \
                GATHER_LOOP(colidx[ebeg + li])                              \
            }                                                               \
            float4 oA = {accA.x * idg, accA.y * idg, accA.z * idg, accA.w * idg}; \
            float4 oB = {accB.x * idg, accB.y * idg, accB.z * idg, accB.w * idg}; \
            *(float4*)(sA + r * 68 + c8 * 8 + 0) = oA;                      \
            *(float4*)(sA + r * 68 + c8 * 8 + 4) = oB;                      \
        }                                                                   \
    }                                                                       \
    __syncthreads();                                                        \
    /* ---- phase B: register-blocked GEMM, W from global (L1-hot) ---- */  \
    const int r0 = t & 15;                                                  \
    const int jq = t >> 4;            /* j0/4 */                            \
    const int j0 = jq * 4;                                                  \
    const float4* __restrict__ Wl4 = (const float4*)Wl;                     \
    const float4* __restrict__ Wr4 = (const float4*)Wr;                     \
    const float4 bias = *(const float4*)(bl + j0);                          \
    float4 acc0 = bias, acc1 = bias, acc2 = bias, acc3 = bias;              \
    _Pragma("unroll 2")                                                     \
    for (int k4 = 0; k4 < 16; ++k4) {                                       \
        float4 b0 = Wl4[(4 * k4 + 0) * 16 + jq];                            \
        float4 b1 = Wl4[(4 * k4 + 1) * 16 + jq];                            \
        float4 b2 = Wl4[(4 * k4 + 2) * 16 + jq];                            \
        float4 b3 = Wl4[(4 * k4 + 3) * 16 + jq];                            \
        float4 a0 = *(const float4*)(sA + (r0 +  0) * 68 + 4 * k4);         \
        float4 a1 = *(const float4*)(sA + (r0 + 16) * 68 + 4 * k4);         \
        float4 a2 = *(const float4*)(sA + (r0 + 32) * 68 + 4 * k4);         \
        float4 a3 = *(const float4*)(sA + (r0 + 48) * 68 + 4 * k4);         \
        FMA4(acc0, a0, b0, b1, b2, b3)                                      \
        FMA4(acc1, a1, b0, b1, b2, b3)                                      \
        FMA4(acc2, a2, b0, b1, b2, b3)                                      \
        FMA4(acc3, a3, b0, b1, b2, b3)                                      \
        b0 = Wr4[(4 * k4 + 0) * 16 + jq];                                   \
        b1 = Wr4[(4 * k4 + 1) * 16 + jq];                                   \
        b2 = Wr4[(4 * k4 + 2) * 16 + jq];                                   \
        b3 = Wr4[(4 * k4 + 3) * 16 + jq];                                   \
        a0 = *(const float4*)(sS + (r0 +  0) * 68 + 4 * k4);                \
        a1 = *(const float4*)(sS + (r0 + 16) * 68 + 4 * k4);                \
        a2 = *(const float4*)(sS + (r0 + 32) * 68 + 4 * k4);                \
        a3 = *(const float4*)(sS + (r0 + 48) * 68 + 4 * k4);                \
        FMA4(acc0, a0, b0, b1, b2, b3)                                      \
        FMA4(acc1, a1, b0, b1, b2, b3)                                      \
        FMA4(acc2, a2, b0, b1, b2, b3)                                      \
        FMA4(acc3, a3, b0, b1, b2, b3)                                      \
    }                                                                       \
    acc0.x = (acc0.x > 0.f) ? acc0.x : SLOPE * acc0.x;                      \
    acc0.y = (acc0.y > 0.f) ? acc0.y : SLOPE * acc0.y;                      \
    acc0.z = (acc0.z > 0.f) ? acc0.z : SLOPE * acc0.z;                      \
    acc0.w = (acc0.w > 0.f) ? acc0.w : SLOPE * acc0.w;                      \
    acc1.x = (acc1.x > 0.f) ? acc1.x : SLOPE * acc1.x;                      \
    acc1.y = (acc1.y > 0.f) ? acc1.y : SLOPE * acc1.y;                      \
    acc1.z = (acc1.z > 0.f) ? acc1.z : SLOPE * acc1.z;                      \
    acc1.w = (acc1.w > 0.f) ? acc1.w : SLOPE * acc1.w;                      \
    acc2.x = (acc2.x > 0.f) ? acc2.x : SLOPE * acc2.x;                      \
    acc2.y = (acc2.y > 0.f) ? acc2.y : SLOPE * acc2.y;                      \
    acc2.z = (acc2.z > 0.f) ? acc2.z : SLOPE * acc2.z;                      \
    acc2.w = (acc2.w > 0.f) ? acc2.w : SLOPE * acc2.w;                      \
    acc3.x = (acc3.x > 0.f) ? acc3.x : SLOPE * acc3.x;                      \
    acc3.y = (acc3.y > 0.f) ? acc3.y : SLOPE * acc3.y;                      \
    acc3.z = (acc3.z > 0.f) ? acc3.z : SLOPE * acc3.z;                      \
    acc3.w = (acc3.w > 0.f) ? acc3.w : SLOPE * acc3.w;

__global__ __launch_bounds__(256, 4) void sage_fused(
    const _Float16* __restrict__ h16_in, _Float16* __restrict__ h16_out,
    const int* __restrict__ rowptr, const int* __restrict__ rowend,
    const int* __restrict__ colidx, const float* __restrict__ invdeg,
    const float* __restrict__ Wl, const float* __restrict__ bl,
    const float* __restrict__ Wr, int n) {
    FUSED_BODY()
    // ---- coalesced epilogue: accs -> sA (dead) -> fp16 global ----
    __syncthreads();            // all phase-B sA reads done before overwrite
    *(float4*)(sA + (r0 +  0) * 68 + j0) = acc0;
    *(float4*)(sA + (r0 + 16) * 68 + j0) = acc1;
    *(float4*)(sA + (r0 + 32) * 68 + j0) = acc2;
    *(float4*)(sA + (r0 + 48) * 68 + j0) = acc3;
    __syncthreads();
    #pragma unroll
    for (int idx = 0; idx < 2; ++idx) {
        int i = t + idx * 256;            // 0..511
        int r = i >> 3, cc = i & 7;       // 8 threads cover one 128B row
        if (r < rows) {
            float4 lo = *(const float4*)(sA + r * 68 + cc * 8 + 0);
            float4 hi = *(const float4*)(sA + r * 68 + cc * 8 + 4);
            _Float16 o[8] = {(_Float16)lo.x, (_Float16)lo.y,
                             (_Float16)lo.z, (_Float16)lo.w,
                             (_Float16)hi.x, (_Float16)hi.y,
                             (_Float16)hi.z, (_Float16)hi.w};
            *(float4*)(h16_out + (size_t)(base + r) * HD + cc * 8) = *(float4*)o;
        }
    }
}

// Layer-3 variant: h3 never hits memory — dot with Wout, cross-wave LDS
// reduction, write out[node] (f32) directly. s_part aliases the dead sidx.
__global__ __launch_bounds__(256, 4) void sage_fused_out(
    const _Float16* __restrict__ h16_in,
    const int* __restrict__ rowptr, const int* __restrict__ rowend,
    const int* __restrict__ colidx, const float* __restrict__ invdeg,
    const float* __restrict__ Wl, const float* __restrict__ bl,
    const float* __restrict__ Wr,
    const float* __restrict__ Wout, const float* __restrict__ bout,
    float* __restrict__ out, int n) {
    FUSED_BODY()
    float* s_part = (float*)sidx;     // [16][64] alias, sidx dead here
    const float4 w4 = *(const float4*)(Wout + j0);
    s_part[jq * 64 + r0 +  0] = acc0.x * w4.x + acc0.y * w4.y + acc0.z * w4.z + acc0.w * w4.w;
    s_part[jq * 64 + r0 + 16] = acc1.x * w4.x + acc1.y * w4.y + acc1.z * w4.z + acc1.w * w4.w;
    s_part[jq * 64 + r0 + 32] = acc2.x * w4.x + acc2.y * w4.y + acc2.z * w4.z + acc2.w * w4.w;
    s_part[jq * 64 + r0 + 48] = acc3.x * w4.x + acc3.y * w4.y + acc3.z * w4.z + acc3.w * w4.w;
    __syncthreads();
    if (t < 64) {
        float sum = 0.f;
        #pragma unroll
        for (int g2 = 0; g2 < 16; ++g2) sum += s_part[g2 * 64 + t];
        if (t < rows) out[base + t] = sum + bout[0];
    }
}

// ---------------------------------------------------------------------------

extern "C" void kernel_launch(void* const* d_in, const int* in_sizes, int n_in,
                              void* d_out, int out_size, void* d_ws, size_t ws_size,
                              hipStream_t stream) {
    const float* x   = (const float*)d_in[0];
    const int* ei    = (const int*)d_in[1];
    const float* Wl1 = (const float*)d_in[2];
    const float* bl1 = (const float*)d_in[3];
    const float* Wr1 = (const float*)d_in[4];
    const float* Wl2 = (const float*)d_in[5];
    const float* bl2 = (const float*)d_in[6];
    const float* Wr2 = (const float*)d_in[7];
    const float* Wl3 = (const float*)d_in[8];
    const float* bl3 = (const float*)d_in[9];
    const float* Wr3 = (const float*)d_in[10];
    const float* Wout = (const float*)d_in[11];
    const float* bout = (const float*)d_in[12];
    float* out = (float*)d_out;

    const int N = in_sizes[0] / HD;       // 50000
    const int E = in_sizes[1] / 2;        // 800000
    const int NB = (N + BNODES - 1) >> BSH;   // 782 buckets
    const int n64 = N * HD;

    // Workspace layout — float4-accessed buffers first (16B alignment).
    _Float16* h16a = (_Float16*)d_ws;                // [N*64] f16
    _Float16* h16b = h16a + (size_t)N * HD;          // [N*64] f16
    int* ebuf     = (int*)(h16b + (size_t)N * HD);   // [NB*SLOT] packed edges
    int* colidx   = ebuf + (size_t)NB * SLOT;        // [NB*SLOT] padded CSR
    int* rowptr   = colidx + (size_t)NB * SLOT;      // [N]
    int* rowend   = rowptr + N;                      // [N]
    float* invdeg = (float*)(rowend + N);            // [N]
    int* bcur     = (int*)(invdeg + N);              // [784]

    hipMemsetAsync(bcur, 0, 784 * sizeof(int), stream);

    part_kernel<<<(E + CHUNK - 1) / CHUNK, 256, 0, stream>>>(ei, bcur, ebuf,
                                                             x, h16a, E, NB, n64);
    bsort_kernel<<<NB, 256, 0, stream>>>(ebuf, bcur, colidx, rowptr, rowend,
                                         invdeg, N);

    const int ggrid = (N + 63) / 64;      // 782 tiles

    sage_fused<<<ggrid, 256, 0, stream>>>(h16a, h16b,
                                          rowptr, rowend, colidx, invdeg,
                                          Wl1, bl1, Wr1, N);
    sage_fused<<<ggrid, 256, 0, stream>>>(h16b, h16a,
                                          rowptr, rowend, colidx, invdeg,
                                          Wl2, bl2, Wr2, N);
    sage_fused_out<<<ggrid, 256, 0, stream>>>(h16a,
                                              rowptr, rowend, colidx, invdeg,
                                              Wl3, bl3, Wr3, Wout, bout, out, N);
}